// Round 1
// baseline (237.332 us; speedup 1.0000x reference)
//
#include <hip/hip_runtime.h>

// Conditional InstanceNorm2d: x[B=32,C=256,H=64,W=64] fp32, style_id[B] int32,
// gamma/beta[S=16,C=256] fp32 -> out fp32.
//
// Dtype forensics (R1-R3 of prior session): all tensors fp32, style_id int32,
// output fp32 (bf16 experiments produced NaN / packed-garbage mismatches).
//
// R4 structure change: wave-per-instance instead of block-per-instance.
//   - One 64-lane wave owns one (b,c) instance: 64 floats/thread, 16 float4
//     loads in flight (4x the MLP of the old 4-loads/thread design).
//   - Reduction is a pure-register __shfl_xor butterfly: no LDS, no
//     __syncthreads, no inter-wave lockstep. Every lane ends with the totals.
//   - 256-thread blocks = 4 fully independent waves; grid = 8192/4 = 2048.
// Traffic is already minimal (read x once = 128 MiB, write out once = 128 MiB);
// the target is pipeline smoothness: the old kernel's vmcnt(0)+barrier phase
// machine idled the memory pipe during reduce. Roofline ~42 us at 6.3 TB/s.

#define HW   4096
#define NC   256
#define NTHR 256

typedef float vfloat4 __attribute__((ext_vector_type(4)));

__global__ __launch_bounds__(NTHR) void cin2d_kernel(
    const float* __restrict__ x,
    const int* __restrict__ style_id,
    const float* __restrict__ gamma,
    const float* __restrict__ beta,
    float* __restrict__ out)
{
    const int wave = threadIdx.x >> 6;
    const int lane = threadIdx.x & 63;
    const int inst = (blockIdx.x << 2) + wave;   // inst = b*NC + c
    const int b = inst >> 8;
    const int c = inst & (NC - 1);

    // 16 KiB instance, 64 lanes x 16 float4: lane's loads stride 1 KiB so each
    // wave-instruction is one fully-coalesced 1 KiB segment.
    const vfloat4* xp = (const vfloat4*)(x + (size_t)inst * HW) + lane;

    vfloat4 d[16];
#pragma unroll
    for (int i = 0; i < 16; ++i) d[i] = xp[i * 64];

    // Style-indexed affine params (tiny, L1/L2-resident). Dependent 2-load
    // chain overlaps with the 16 KiB x stream above.
    const int sid = style_id[b];
    const float g  = gamma[sid * NC + c];
    const float be = beta[sid * NC + c];

    float s = 0.0f, q = 0.0f;
#pragma unroll
    for (int i = 0; i < 16; ++i) {
#pragma unroll
        for (int j = 0; j < 4; ++j) {
            const float t = d[i][j];
            s += t;
            q = fmaf(t, t, q);
        }
    }

    // Wave-wide butterfly reduction: 6 steps, all 64 lanes end with the
    // totals. No LDS, no barrier, waves stay fully decoupled.
#pragma unroll
    for (int off = 1; off < 64; off <<= 1) {
        s += __shfl_xor(s, off, 64);
        q += __shfl_xor(q, off, 64);
    }

    const float inv_n = 1.0f / (float)HW;
    const float mean = s * inv_n;
    float var = fmaf(-mean, mean, q * inv_n);   // E[x^2] - mean^2 (biased)
    var = var < 0.0f ? 0.0f : var;
    const float rstd = rsqrtf(var + 1e-5f);

    const float scale = g * rstd;
    const float shift = fmaf(-mean, scale, be);

    vfloat4* op = (vfloat4*)(out + (size_t)inst * HW) + lane;
#pragma unroll
    for (int i = 0; i < 16; ++i) {
        vfloat4 w;
#pragma unroll
        for (int j = 0; j < 4; ++j) w[j] = fmaf(d[i][j], scale, shift);
        op[i * 64] = w;
    }
}

extern "C" void kernel_launch(void* const* d_in, const int* in_sizes, int n_in,
                              void* d_out, int out_size, void* d_ws, size_t ws_size,
                              hipStream_t stream) {
    const float* x     = (const float*)d_in[0];
    const int*   sid   = (const int*)d_in[1];
    const float* gamma = (const float*)d_in[2];
    const float* beta  = (const float*)d_in[3];
    float* out = (float*)d_out;

    const int B = 32, C = 256;
    dim3 grid((B * C) / 4), block(NTHR);   // 4 waves/block, 1 instance/wave
    hipLaunchKernelGGL(cin2d_kernel, grid, block, 0, stream,
                       x, sid, gamma, beta, out);
}

// Round 2
// 234.700 us; speedup vs baseline: 1.0112x; 1.0112x over previous
//
#include <hip/hip_runtime.h>

// Conditional InstanceNorm2d: x[B=32,C=256,H=64,W=64] fp32, style_id[B] int32,
// gamma/beta[S=16,C=256] fp32 -> out fp32.
//
// Dtype forensics (prior session R1-R3): all tensors fp32, style_id int32,
// output fp32 (bf16 experiments -> NaN / packed-garbage mismatches).
//
// R5: fix the R4 rematerialization bug.
//   R4 (wave-per-instance, d[16] in regs) came back with VGPR_Count=40 --
//   impossible for 64 live data VGPRs, and WRITE_SIZE showed no scratch:
//   the compiler re-LOADED x in the store phase (legal: x is __restrict__,
//   never written) => 384 MiB logical traffic + L2-latency epilogue, 80.7 us
//   at only 2.5 TB/s with VALUBusy 3.7% (nothing saturated).
//   Fix: pin d[] with asm("" : "+v") after the load phase -- values now
//   originate from inline asm, so loads cannot be rematerialized. Expect
//   VGPR ~90 (5 waves/SIMD, still plenty to hide ~900cy HBM latency: a wave
//   in load phase has 16 KiB outstanding; ~9 KiB/CU sustains 6.3 TB/s).
//   Also: 1-wave (64-thread) blocks for finest scheduler granularity; 4
//   partial accumulator chains (VALU is idle; shortens per-wave latency).
// One-pass roofline: 128 MiB read + 128 MiB write ~= 42 us at 6.3 TB/s.

#define HW   4096
#define NC   256
#define NTHR 64

typedef float vfloat4 __attribute__((ext_vector_type(4)));

__global__ __launch_bounds__(NTHR) void cin2d_kernel(
    const float* __restrict__ x,
    const int* __restrict__ style_id,
    const float* __restrict__ gamma,
    const float* __restrict__ beta,
    float* __restrict__ out)
{
    const int lane = threadIdx.x;        // 0..63, one wave per block
    const int inst = blockIdx.x;         // inst = b*NC + c
    const int b = inst >> 8;
    const int c = inst & (NC - 1);

    // 16 KiB instance, 64 lanes x 16 float4: each wave-instruction covers one
    // fully-coalesced 1 KiB segment.
    const vfloat4* xp = (const vfloat4*)(x + (size_t)inst * HW) + lane;

    vfloat4 d[16];
#pragma unroll
    for (int i = 0; i < 16; ++i) d[i] = xp[i * 64];

    // Pin the loaded tile in VGPRs: the asm redefines each value, so the
    // compiler cannot rematerialize the global loads in the store phase.
#pragma unroll
    for (int i = 0; i < 16; ++i) {
        asm volatile("" : "+v"(d[i]));
    }

    // Style-indexed affine params (tiny, L1/L2-resident); dependent 2-load
    // chain overlaps with the x stream above.
    const int sid = style_id[b];
    const float g  = gamma[sid * NC + c];
    const float be = beta[sid * NC + c];

    // 4 independent accumulator chains (dep latency ~4cy/fma; 16 deep each).
    float s0 = 0.f, s1 = 0.f, s2 = 0.f, s3 = 0.f;
    float q0 = 0.f, q1 = 0.f, q2 = 0.f, q3 = 0.f;
#pragma unroll
    for (int i = 0; i < 16; ++i) {
        s0 += d[i][0];  q0 = fmaf(d[i][0], d[i][0], q0);
        s1 += d[i][1];  q1 = fmaf(d[i][1], d[i][1], q1);
        s2 += d[i][2];  q2 = fmaf(d[i][2], d[i][2], q2);
        s3 += d[i][3];  q3 = fmaf(d[i][3], d[i][3], q3);
    }
    float s = (s0 + s1) + (s2 + s3);
    float q = (q0 + q1) + (q2 + q3);

    // Wave-wide butterfly: 6 steps, all 64 lanes end with the totals.
    // No LDS, no barrier, waves stay fully decoupled.
#pragma unroll
    for (int off = 1; off < 64; off <<= 1) {
        s += __shfl_xor(s, off, 64);
        q += __shfl_xor(q, off, 64);
    }

    const float inv_n = 1.0f / (float)HW;
    const float mean = s * inv_n;
    float var = fmaf(-mean, mean, q * inv_n);   // E[x^2] - mean^2 (biased)
    var = var < 0.0f ? 0.0f : var;
    const float rstd = rsqrtf(var + 1e-5f);

    const float scale = g * rstd;
    const float shift = fmaf(-mean, scale, be);

    vfloat4* op = (vfloat4*)(out + (size_t)inst * HW) + lane;
#pragma unroll
    for (int i = 0; i < 16; ++i) {
        vfloat4 w;
#pragma unroll
        for (int j = 0; j < 4; ++j) w[j] = fmaf(d[i][j], scale, shift);
        op[i * 64] = w;
    }
}

extern "C" void kernel_launch(void* const* d_in, const int* in_sizes, int n_in,
                              void* d_out, int out_size, void* d_ws, size_t ws_size,
                              hipStream_t stream) {
    const float* x     = (const float*)d_in[0];
    const int*   sid   = (const int*)d_in[1];
    const float* gamma = (const float*)d_in[2];
    const float* beta  = (const float*)d_in[3];
    float* out = (float*)d_out;

    const int B = 32, C = 256;
    dim3 grid(B * C), block(NTHR);       // one 64-lane wave per instance
    hipLaunchKernelGGL(cin2d_kernel, grid, block, 0, stream,
                       x, sid, gamma, beta, out);
}